// Round 26
// baseline (82.216 us; speedup 1.0000x reference)
//
#include <hip/hip_runtime.h>

// Loss = ||corr_norm(W1)-corr_norm(W2)||^2 + ||corr_norm(B1)-corr_norm(B2)||^2
// within_s  ∝ G1_s - 128*P2_s - 16384*m_s m_s^T ; between_s ∝ P2_s = rm^T rm.
//
// Measured: K1≈20.5us, GEMM≈18.4us (XCD/L2-grouping, r24), K5≈5us (r25),
// K2+K6+gaps≈20us -> gaps dominate the tail. r26: K2 dispatch ELIMINATED —
// between-GEMM blocks compute slice-mean ml locally (L2 xm, overlapped with
// big-GEMM blocks), stage rm=xm-ml directly into swizzled LDS (no rmT
// global round-trip); diag blocks (1 per tile/slice, race-free) write m
// for K5. Pipeline 5 -> 4 dispatches.

typedef float f32x2 __attribute__((ext_vector_type(2)));
typedef float f32x4 __attribute__((ext_vector_type(4)));
typedef short bf16x8 __attribute__((ext_vector_type(8)));
typedef unsigned short u16x4 __attribute__((ext_vector_type(4)));

// ---- ws layout (bytes); P1 last so split-K partial count adapts to ws_size ----
static constexpr size_t OFF_RT    = 0;                         // bf16 R_T [2][768][16384]  = 50,331,648
static constexpr size_t OFF_XM    = 50331648;                  // f32 xm [2][128][768]      = 786,432
static constexpr size_t OFF_M     = 51118080;                  // f32 m  [2][768]           = 6,144
static constexpr size_t OFF_P2    = 51517440;                  // f32 [42][128*128]         = 2,752,512
static constexpr size_t OFF_BPART = 54269952;                  // f32 [672][16]             = 43,008
static constexpr size_t OFF_P1    = 54355968;                  // f32 [42*ksplit][128*128]

__device__ __forceinline__ unsigned int f2bf_u32(float f) {
  union { float f; unsigned int u; } v; v.f = f;
  unsigned int u = v.u;
  unsigned int lsb = (u >> 16) & 1u;
  u += 0x7fffu + lsb;
  return u >> 16;
}

__device__ __forceinline__ void gload_lds16(const void* g, void* l) {
  __builtin_amdgcn_global_load_lds(
      (const __attribute__((address_space(1))) unsigned int*)g,
      (__attribute__((address_space(3))) unsigned int*)l, 16, 0, 0);
}

// ---------------- K1 v6: LDS bf16 transpose-convert + f32 register means ----------------
__global__ void __launch_bounds__(256) k1_means_convert(const float* __restrict__ x,
                                                        float* __restrict__ xm,
                                                        unsigned short* __restrict__ RT) {
  __shared__ unsigned short T[128][130];
  __shared__ float pm[4][128];
  int bid = blockIdx.x;
  int dt = bid % 6, borig = bid / 6;
  int s = borig & 1, b = borig >> 1;
  int tid = threadIdx.x, w = tid >> 6, lane = tid & 63;

  const float* xb = x + (size_t)borig * (128 * 768) + dt * 128 + 2 * lane;
  float cs0 = 0.f, cs1 = 0.f;
#pragma unroll
  for (int g = 0; g < 8; ++g) {
    int n0 = w * 32 + g * 4;
    f32x2 a0 = *reinterpret_cast<const f32x2*>(xb + (size_t)(n0 + 0) * 768);
    f32x2 a1 = *reinterpret_cast<const f32x2*>(xb + (size_t)(n0 + 1) * 768);
    f32x2 a2 = *reinterpret_cast<const f32x2*>(xb + (size_t)(n0 + 2) * 768);
    f32x2 a3 = *reinterpret_cast<const f32x2*>(xb + (size_t)(n0 + 3) * 768);
    cs0 += a0[0] + a1[0] + a2[0] + a3[0];
    cs1 += a0[1] + a1[1] + a2[1] + a3[1];
    u16x4 p0, p1;
    p0[0] = (unsigned short)f2bf_u32(a0[0]); p0[1] = (unsigned short)f2bf_u32(a1[0]);
    p0[2] = (unsigned short)f2bf_u32(a2[0]); p0[3] = (unsigned short)f2bf_u32(a3[0]);
    p1[0] = (unsigned short)f2bf_u32(a0[1]); p1[1] = (unsigned short)f2bf_u32(a1[1]);
    p1[2] = (unsigned short)f2bf_u32(a2[1]); p1[3] = (unsigned short)f2bf_u32(a3[1]);
    *reinterpret_cast<u16x4*>(&T[2 * lane + 0][n0]) = p0;
    *reinterpret_cast<u16x4*>(&T[2 * lane + 1][n0]) = p1;
  }
  *reinterpret_cast<f32x2*>(&pm[w][2 * lane]) = f32x2{cs0, cs1};
  __syncthreads();

  if (tid < 128) {
    float mv = (pm[0][tid] + pm[1][tid] + pm[2][tid] + pm[3][tid]) * (1.f / 128.f);
    xm[((size_t)(s * 128 + b)) * 768ull + dt * 128 + tid] = mv;
  }

  int half = lane >> 5;
  int nb = (lane & 31) * 4;
  unsigned short* rtbase = RT + (size_t)s * (768ull * 16384ull) + (size_t)(b * 128 + nb);
#pragma unroll
  for (int i = 0; i < 16; ++i) {
    int d_loc = w * 32 + 2 * i + half;
    uint2 v = *reinterpret_cast<const uint2*>(&T[d_loc][nb]);
    *reinterpret_cast<uint2*>(rtbase + (size_t)(dt * 128 + d_loc) * 16384ull) = v;
  }
}

// ---------------- K3: merged A^T A GEMM + fused between (slice-mean + rm staging) ----------------
__device__ __forceinline__ void stage_tile(const unsigned short* __restrict__ g, int KP, int k0,
                                           unsigned short* lds, int wave, int lane) {
#pragma unroll
  for (int i = 0; i < 4; ++i) {
    int cb = (i * 4 + wave) * 64;       // wave-uniform chunk base
    int chunk = cb + lane;
    int r = chunk >> 3, sl = chunk & 7;
    int ss = sl ^ (r & 7);              // inverse-swizzled global source
    const unsigned short* src = g + (size_t)r * KP + (k0 + ss * 8);
    gload_lds16(src, lds + (size_t)cb * 8);
  }
}

// fused rm staging: LDS[c*8+j] = f2bf(xm[s][b=half*64+(sl^(r&7))*8+j][tile*128+r] - ml[r])
// -- byte-compatible with stage_tile(rmT,...) layout so read_frag is unchanged.
__device__ __forceinline__ void stage_rm_tile(unsigned short* lds, const float* __restrict__ xmb,
                                              const float* mlbase, int half, int tid) {
  for (int c = tid; c < 1024; c += 256) {
    int r = c >> 3, sl = c & 7, ss = sl ^ (r & 7);
    int b0 = half * 64 + ss * 8;
    float mv = mlbase[r];
    const float* col = xmb + r;
    u16x4 lo, hi;
#pragma unroll
    for (int j = 0; j < 4; ++j) lo[j] = (unsigned short)f2bf_u32(col[(size_t)(b0 + j) * 768] - mv);
#pragma unroll
    for (int j = 0; j < 4; ++j) hi[j] = (unsigned short)f2bf_u32(col[(size_t)(b0 + 4 + j) * 768] - mv);
    u16x4* dst = reinterpret_cast<u16x4*>(lds + (size_t)c * 8);
    dst[0] = lo; dst[1] = hi;
  }
}

__device__ __forceinline__ bf16x8 read_frag(const unsigned short* lds, int row, int slot) {
  int chunk = row * 8 + (slot ^ (row & 7));   // swizzled read
  return *reinterpret_cast<const bf16x8*>(lds + chunk * 8);
}

__device__ __forceinline__ void tp2tile(int tp, int& td, int& te) {
  td = 0; int t2 = tp;
  while (t2 >= 6 - td) { t2 -= 6 - td; ++td; }
  te = td + t2;
}

__global__ void __launch_bounds__(256) gemm_ata(const unsigned short* __restrict__ Rbig,
                                                const float* __restrict__ xm,
                                                float* __restrict__ mOut,
                                                float* __restrict__ P1, float* __restrict__ P2,
                                                int ksplit) {
  __shared__ unsigned short Ta[2][128 * 64];
  __shared__ unsigned short Tb[2][128 * 64];
  __shared__ float ml[256];
  int bid = blockIdx.x;
  int nbig = 42 * ksplit;
  bool isBetween = (bid >= nbig);
  int s, tp, step0, step1; float* pout;
  if (!isBetween) {
    // XCD-grouped order (ksplit=12: nbig=504=8*63). [r24: CONFIRMED -6.4us]
    int logical;
    if (nbig == 504) logical = (bid & 7) * 63 + (bid >> 3);
    else             logical = bid;
    int g = logical / 21; tp = logical % 21;
    s = g & 1; int c = g >> 1;
    step0 = (256 * c) / ksplit; step1 = (256 * (c + 1)) / ksplit;
    pout = P1 + (size_t)((tp * 2 + s) * ksplit + c) * (128 * 128);  // canonical for K5
  } else {                                       // between GEMM: K=128, fused K2
    int b2 = bid - nbig;
    s = b2 & 1; tp = b2 >> 1; step0 = 0; step1 = 2;
    pout = P2 + (size_t)b2 * (128 * 128);
  }
  int td, te; tp2tile(tp, td, te);
  bool diag = (td == te);
  int tid = threadIdx.x, wave = tid >> 6, lane = tid & 63;
  int m_off = (wave >> 1) * 64, n_off = (wave & 1) * 64;
  int row_a = m_off + (lane & 15), row_b = n_off + (lane & 15);
  f32x4 acc[4][4];
#pragma unroll
  for (int i = 0; i < 4; ++i)
#pragma unroll
    for (int j = 0; j < 4; ++j) { acc[i][j][0]=0.f; acc[i][j][1]=0.f; acc[i][j][2]=0.f; acc[i][j][3]=0.f; }

  const unsigned short* Ra = nullptr; const unsigned short* Rb = nullptr;
  const int KP = 16384;
  if (!isBetween) {
    Ra = Rbig + (size_t)s * (768ull * 16384ull) + (size_t)(td * 128) * KP;
    Rb = Rbig + (size_t)s * (768ull * 16384ull) + (size_t)(te * 128) * KP;
    // prologue: stage first tile
    stage_tile(Ra, KP, step0 * 64, Ta[0], wave, lane);
    if (!diag) stage_tile(Rb, KP, step0 * 64, Tb[0], wave, lane);
  } else {
    // fused K2: local slice-means for both tiles (deterministic fixed order)
    {
      int tile = (tid < 128) ? td : te;
      int dl = tid & 127;
      const float* base = xm + (size_t)s * (128 * 768) + tile * 128 + dl;
      float a0 = 0.f, a1 = 0.f, a2 = 0.f, a3 = 0.f;
      for (int b = 0; b < 128; b += 4) {
        a0 += base[(size_t)(b + 0) * 768]; a1 += base[(size_t)(b + 1) * 768];
        a2 += base[(size_t)(b + 2) * 768]; a3 += base[(size_t)(b + 3) * 768];
      }
      float mv = ((a0 + a1) + (a2 + a3)) * (1.f / 128.f);
      ml[tid] = mv;
      if (diag && tid < 128) mOut[s * 768 + td * 128 + dl] = mv;  // each (s,tile) once
    }
    __syncthreads();
    const float* xmb_a = xm + (size_t)s * (128 * 768) + td * 128;
    stage_rm_tile(Ta[0], xmb_a, &ml[0], 0, tid);
    stage_rm_tile(Ta[1], xmb_a, &ml[0], 1, tid);
    if (!diag) {
      const float* xmb_b = xm + (size_t)s * (128 * 768) + te * 128;
      stage_rm_tile(Tb[0], xmb_b, &ml[128], 0, tid);
      stage_rm_tile(Tb[1], xmb_b, &ml[128], 1, tid);
    }
  }
  __syncthreads();

  int cur = 0;
  for (int kt = step0; kt < step1; ++kt) {
    if (!isBetween && kt + 1 < step1) {   // prefetch next tile (overlaps MFMA)
      stage_tile(Ra, KP, (kt + 1) * 64, Ta[cur ^ 1], wave, lane);
      if (!diag) stage_tile(Rb, KP, (kt + 1) * 64, Tb[cur ^ 1], wave, lane);
    }
    const unsigned short* Bsrc = diag ? Ta[cur] : Tb[cur];
#pragma unroll
    for (int ks = 0; ks < 2; ++ks) {
      bf16x8 a[4], b[4];
      int slot = ks * 4 + (lane >> 4);
#pragma unroll
      for (int mi = 0; mi < 4; ++mi) a[mi] = read_frag(Ta[cur], row_a + mi * 16, slot);
#pragma unroll
      for (int ni = 0; ni < 4; ++ni) b[ni] = read_frag(Bsrc, row_b + ni * 16, slot);
#pragma unroll
      for (int mi = 0; mi < 4; ++mi)
#pragma unroll
        for (int ni = 0; ni < 4; ++ni)
          acc[mi][ni] = __builtin_amdgcn_mfma_f32_16x16x32_bf16(a[mi], b[ni], acc[mi][ni], 0, 0, 0);
    }
    __syncthreads();   // staged tile landed + all reads of buf[cur] done
    cur ^= 1;
  }
  int hi = lane >> 4, lo = lane & 15;
#pragma unroll
  for (int mi = 0; mi < 4; ++mi)
#pragma unroll
    for (int ni = 0; ni < 4; ++ni)
#pragma unroll
      for (int r = 0; r < 4; ++r) {
        int rr = m_off + mi * 16 + hi * 4 + r;
        int cc = n_off + ni * 16 + lo;
        pout[rr * 128 + cc] = acc[mi][ni][r];
      }
}

// ---------------- K5: 10-way partial sums, grid 672, compile-time KS, NO fence ----------------
template <int KS>
__global__ void __launch_bounds__(256) k5_elem(const float* __restrict__ P1,
                                               const float* __restrict__ P2,
                                               const float* __restrict__ m,
                                               float* __restrict__ bpart, int ksplit_rt) {
  __shared__ float red[4][10];
  int bid = blockIdx.x;                 // 0..671
  int tp = bid >> 5, sub = bid & 31;
  int td, te; tp2tile(tp, td, te);
  bool diagTile = (td == te);
  float mult = diagTile ? 1.0f : 2.0f;
  int t = threadIdx.x;
  int lane = t & 63, w = t >> 6;
  int ksplit = (KS > 0) ? KS : ksplit_rt;
  float v[10];
#pragma unroll
  for (int j = 0; j < 10; ++j) v[j] = 0.f;

#pragma unroll
  for (int k = 0; k < 2; ++k) {
    int idx = sub * 512 + k * 256 + t;   // 0..16383 within tile
    int r = idx >> 7, cc = idx & 127;
    int d = td * 128 + r, e = te * 128 + cc;
    float W[2], B[2];
#pragma unroll
    for (int s = 0; s < 2; ++s) {
      const float* base1 = P1 + (size_t)((tp * 2 + s) * ksplit) * 16384ull + idx;
      float g1 = 0.f;
#pragma unroll
      for (int c6 = 0; c6 < ((KS > 0) ? KS : 16); ++c6) {
        if (KS > 0 || c6 < ksplit) g1 += base1[(size_t)c6 * 16384ull];
      }
      float p2v = P2[(size_t)(tp * 2 + s) * 16384ull + idx];
      W[s] = g1 - 128.0f * p2v - 16384.0f * m[s * 768 + d] * m[s * 768 + e];
      B[s] = p2v;
    }
    v[0] += W[0] * W[0] * mult;  v[1] += W[1] * W[1] * mult;  v[2] += W[0] * W[1] * mult;
    v[3] += B[0] * B[0] * mult;  v[4] += B[1] * B[1] * mult;  v[5] += B[0] * B[1] * mult;
    if (diagTile && r == cc) {
      v[6] += W[0] * W[0];  v[7] += W[1] * W[1];
      v[8] += B[0] * B[0];  v[9] += B[1] * B[1];
    }
  }
#pragma unroll
  for (int off = 32; off; off >>= 1)
#pragma unroll
    for (int j = 0; j < 10; ++j) v[j] += __shfl_down(v[j], off, 64);
  if (lane == 0)
#pragma unroll
    for (int j = 0; j < 10; ++j) red[w][j] = v[j];
  __syncthreads();
  if (t < 10) bpart[bid * 16 + t] = red[0][t] + red[1][t] + red[2][t] + red[3][t];
}

// ---------------- K6: final reduce + normalized combine ----------------
__global__ void __launch_bounds__(256) k6_final(const float* __restrict__ bpart,
                                                float* __restrict__ out) {
  __shared__ float red[4][10];
  float acc[10];
#pragma unroll
  for (int j = 0; j < 10; ++j) acc[j] = 0.f;
  for (int i = threadIdx.x; i < 672; i += 256)
#pragma unroll
    for (int j = 0; j < 10; ++j) acc[j] += bpart[i * 16 + j];
  int lane = threadIdx.x & 63, w = threadIdx.x >> 6;
#pragma unroll
  for (int off = 32; off; off >>= 1)
#pragma unroll
    for (int j = 0; j < 10; ++j) acc[j] += __shfl_down(acc[j], off, 64);
  if (lane == 0)
#pragma unroll
    for (int j = 0; j < 10; ++j) red[w][j] = acc[j];
  __syncthreads();
  if (threadIdx.x == 0) {
    float S[10];
#pragma unroll
    for (int j = 0; j < 10; ++j) S[j] = red[0][j] + red[1][j] + red[2][j] + red[3][j];
    float lw = S[0] / S[6] + S[1] / S[7] - 2.0f * S[2] / sqrtf(S[6] * S[7]);
    float lb = S[3] / S[8] + S[4] / S[9] - 2.0f * S[5] / sqrtf(S[8] * S[9]);
    out[0] = lw + lb;
  }
}

extern "C" void kernel_launch(void* const* d_in, const int* in_sizes, int n_in,
                              void* d_out, int out_size, void* d_ws, size_t ws_size,
                              hipStream_t stream) {
  const float* x = (const float*)d_in[0];
  char* ws = (char*)d_ws;
  unsigned short* RT  = (unsigned short*)(ws + OFF_RT);
  float* xm           = (float*)(ws + OFF_XM);
  float* m            = (float*)(ws + OFF_M);
  float* P2           = (float*)(ws + OFF_P2);
  float* bpart        = (float*)(ws + OFF_BPART);
  float* P1           = (float*)(ws + OFF_P1);
  float* out          = (float*)d_out;

  // split-K = 12: nbig = 504 = 8*63 -> XCD swizzle bijective & ACTIVE
  size_t availP1 = (ws_size > OFF_P1) ? (ws_size - OFF_P1) : 0;
  int ksplit = (int)(availP1 / (42ull * 128 * 128 * 4));
  if (ksplit > 12) ksplit = 12;
  if (ksplit < 1) ksplit = 1;

  hipLaunchKernelGGL(k1_means_convert, dim3(1536), dim3(256), 0, stream, x, xm, RT);
  hipLaunchKernelGGL(gemm_ata, dim3(42 * ksplit + 42), dim3(256), 0, stream,
                     RT, xm, m, P1, P2, ksplit);
  if (ksplit == 12) {
    hipLaunchKernelGGL((k5_elem<12>), dim3(672), dim3(256), 0, stream,
                       P1, P2, m, bpart, ksplit);
  } else if (ksplit == 11) {
    hipLaunchKernelGGL((k5_elem<11>), dim3(672), dim3(256), 0, stream,
                       P1, P2, m, bpart, ksplit);
  } else {
    hipLaunchKernelGGL((k5_elem<0>), dim3(672), dim3(256), 0, stream,
                       P1, P2, m, bpart, ksplit);
  }
  hipLaunchKernelGGL(k6_final, dim3(1), dim3(256), 0, stream, bpart, out);
}

// Round 27
// 71.063 us; speedup vs baseline: 1.1569x; 1.1569x over previous
//
#include <hip/hip_runtime.h>

// Loss = ||corr_norm(W1)-corr_norm(W2)||^2 + ||corr_norm(B1)-corr_norm(B2)||^2
// within_s  ∝ G1_s - 128*P2_s - 16384*m_s m_s^T ; between_s ∝ P2_s = rm^T rm.
//
// BEST-KNOWN BUILD (r24: 71.04us, reverted after r26 fusion regression).
// Measured components: K1≈20.5 (HBM transpose floor; 3 rewrites ~equal),
// GEMM≈18.4 (XCD/L2-grouped split-K, r24 confirmed -6.4us), K5≈5 (r25),
// K2≈2.5, K6≈1.5, remainder = launch/drain overhead (resists naive fusion:
// r17/r20 fence +60us, r26 tail-fusion +11us).

typedef float f32x2 __attribute__((ext_vector_type(2)));
typedef float f32x4 __attribute__((ext_vector_type(4)));
typedef short bf16x8 __attribute__((ext_vector_type(8)));
typedef unsigned short u16x4 __attribute__((ext_vector_type(4)));

// ---- ws layout (bytes); P1 last so split-K partial count adapts to ws_size ----
static constexpr size_t OFF_RT    = 0;                         // bf16 R_T [2][768][16384]  = 50,331,648
static constexpr size_t OFF_XM    = 50331648;                  // f32 xm [2][128][768]      = 786,432
static constexpr size_t OFF_M     = 51118080;                  // f32 m  [2][768]           = 6,144
static constexpr size_t OFF_RM    = 51124224;                  // bf16 rm_T [2][768][128]   = 393,216
static constexpr size_t OFF_P2    = 51517440;                  // f32 [42][128*128]         = 2,752,512
static constexpr size_t OFF_BPART = 54269952;                  // f32 [672][16]             = 43,008
static constexpr size_t OFF_P1    = 54355968;                  // f32 [42*ksplit][128*128]

__device__ __forceinline__ unsigned int f2bf_u32(float f) {
  union { float f; unsigned int u; } v; v.f = f;
  unsigned int u = v.u;
  unsigned int lsb = (u >> 16) & 1u;
  u += 0x7fffu + lsb;
  return u >> 16;
}

__device__ __forceinline__ void gload_lds16(const void* g, void* l) {
  __builtin_amdgcn_global_load_lds(
      (const __attribute__((address_space(1))) unsigned int*)g,
      (__attribute__((address_space(3))) unsigned int*)l, 16, 0, 0);
}

// ---------------- K1 v6: LDS bf16 transpose-convert + f32 register means ----------------
__global__ void __launch_bounds__(256) k1_means_convert(const float* __restrict__ x,
                                                        float* __restrict__ xm,
                                                        unsigned short* __restrict__ RT) {
  __shared__ unsigned short T[128][130];
  __shared__ float pm[4][128];
  int bid = blockIdx.x;
  int dt = bid % 6, borig = bid / 6;
  int s = borig & 1, b = borig >> 1;
  int tid = threadIdx.x, w = tid >> 6, lane = tid & 63;

  const float* xb = x + (size_t)borig * (128 * 768) + dt * 128 + 2 * lane;
  float cs0 = 0.f, cs1 = 0.f;
#pragma unroll
  for (int g = 0; g < 8; ++g) {
    int n0 = w * 32 + g * 4;
    f32x2 a0 = *reinterpret_cast<const f32x2*>(xb + (size_t)(n0 + 0) * 768);
    f32x2 a1 = *reinterpret_cast<const f32x2*>(xb + (size_t)(n0 + 1) * 768);
    f32x2 a2 = *reinterpret_cast<const f32x2*>(xb + (size_t)(n0 + 2) * 768);
    f32x2 a3 = *reinterpret_cast<const f32x2*>(xb + (size_t)(n0 + 3) * 768);
    cs0 += a0[0] + a1[0] + a2[0] + a3[0];
    cs1 += a0[1] + a1[1] + a2[1] + a3[1];
    u16x4 p0, p1;
    p0[0] = (unsigned short)f2bf_u32(a0[0]); p0[1] = (unsigned short)f2bf_u32(a1[0]);
    p0[2] = (unsigned short)f2bf_u32(a2[0]); p0[3] = (unsigned short)f2bf_u32(a3[0]);
    p1[0] = (unsigned short)f2bf_u32(a0[1]); p1[1] = (unsigned short)f2bf_u32(a1[1]);
    p1[2] = (unsigned short)f2bf_u32(a2[1]); p1[3] = (unsigned short)f2bf_u32(a3[1]);
    *reinterpret_cast<u16x4*>(&T[2 * lane + 0][n0]) = p0;
    *reinterpret_cast<u16x4*>(&T[2 * lane + 1][n0]) = p1;
  }
  *reinterpret_cast<f32x2*>(&pm[w][2 * lane]) = f32x2{cs0, cs1};
  __syncthreads();

  if (tid < 128) {
    float mv = (pm[0][tid] + pm[1][tid] + pm[2][tid] + pm[3][tid]) * (1.f / 128.f);
    xm[((size_t)(s * 128 + b)) * 768ull + dt * 128 + tid] = mv;
  }

  int half = lane >> 5;
  int nb = (lane & 31) * 4;
  unsigned short* rtbase = RT + (size_t)s * (768ull * 16384ull) + (size_t)(b * 128 + nb);
#pragma unroll
  for (int i = 0; i < 16; ++i) {
    int d_loc = w * 32 + 2 * i + half;
    uint2 v = *reinterpret_cast<const uint2*>(&T[d_loc][nb]);
    *reinterpret_cast<uint2*>(rtbase + (size_t)(dt * 128 + d_loc) * 16384ull) = v;
  }
}

// ---------------- K2 v2: slice mean + bf16 residual-mean transpose ----------------
__global__ void __launch_bounds__(256) k2_slice_mean(const float* __restrict__ xm,
                                                     float* __restrict__ m,
                                                     unsigned short* __restrict__ rmT) {
  __shared__ float pm[4][64];
  __shared__ float ml[64];
  int s = blockIdx.x / 12, dg = blockIdx.x % 12;
  int t = threadIdx.x;
  int d_loc = t & 63, part = t >> 6;
  int d = dg * 64 + d_loc;
  const float* base = xm + (size_t)s * 128ull * 768ull + d;
  float acc = 0.f;
#pragma unroll 4
  for (int i = 0; i < 32; ++i) acc += base[(size_t)(part * 32 + i) * 768ull];
  pm[part][d_loc] = acc;
  __syncthreads();
  if (t < 64) {
    float mv = (pm[0][t] + pm[1][t] + pm[2][t] + pm[3][t]) * (1.f / 128.f);
    m[s * 768 + dg * 64 + t] = mv;
    ml[t] = mv;
  }
  __syncthreads();
  float mv = ml[d_loc];
  unsigned short* rt = rmT + ((size_t)s * 768ull + d) * 128ull + part * 32;
#pragma unroll 4
  for (int i = 0; i < 32; ++i)
    rt[i] = (unsigned short)f2bf_u32(base[(size_t)(part * 32 + i) * 768ull] - mv);
}

// ---------------- K3: merged A^T A GEMM, dbuf, diag-skip, XCD-grouped block order ----------------
__device__ __forceinline__ void stage_tile(const unsigned short* __restrict__ g, int KP, int k0,
                                           unsigned short* lds, int wave, int lane) {
#pragma unroll
  for (int i = 0; i < 4; ++i) {
    int cb = (i * 4 + wave) * 64;       // wave-uniform chunk base
    int chunk = cb + lane;
    int r = chunk >> 3, sl = chunk & 7;
    int ss = sl ^ (r & 7);              // inverse-swizzled global source
    const unsigned short* src = g + (size_t)r * KP + (k0 + ss * 8);
    gload_lds16(src, lds + (size_t)cb * 8);
  }
}

__device__ __forceinline__ bf16x8 read_frag(const unsigned short* lds, int row, int slot) {
  int chunk = row * 8 + (slot ^ (row & 7));   // swizzled read
  return *reinterpret_cast<const bf16x8*>(lds + chunk * 8);
}

__device__ __forceinline__ void tp2tile(int tp, int& td, int& te) {
  td = 0; int t2 = tp;
  while (t2 >= 6 - td) { t2 -= 6 - td; ++td; }
  te = td + t2;
}

__global__ void __launch_bounds__(256) gemm_ata(const unsigned short* __restrict__ Rbig,
                                                const unsigned short* __restrict__ rmT,
                                                float* __restrict__ P1, float* __restrict__ P2,
                                                int ksplit) {
  __shared__ unsigned short Ta[2][128 * 64];
  __shared__ unsigned short Tb[2][128 * 64];
  int bid = blockIdx.x;
  int nbig = 42 * ksplit;
  const unsigned short* R; size_t slice_stride; int KP;
  int s, tp, step0, step1; float* pout;
  if (bid < nbig) {
    // XCD-grouped order (active when ksplit=12: nbig=504=8*63). HW dispatch
    // round-robins raw bid over 8 XCDs, so logical=(bid&7)*63+(bid>>3) puts
    // logical 0..62 on XCD0, 63..125 on XCD1, ... Each (s,c) group of 21
    // tiles (logical/21) then runs on ~one XCD; its 6 panel-chunks (~2.3MB)
    // stay L2-resident there. [r24: CONFIRMED -6.4us]
    int logical;
    if (nbig == 504) logical = (bid & 7) * 63 + (bid >> 3);
    else             logical = bid;
    int g = logical / 21; tp = logical % 21;
    s = g & 1; int c = g >> 1;
    R = Rbig; slice_stride = 768ull * 16384ull; KP = 16384;
    step0 = (256 * c) / ksplit; step1 = (256 * (c + 1)) / ksplit;
    pout = P1 + (size_t)((tp * 2 + s) * ksplit + c) * (128 * 128);  // canonical for K5
  } else {                                       // between GEMM: K=128
    int b2 = bid - nbig;
    R = rmT; slice_stride = 768ull * 128ull; KP = 128;
    s = b2 & 1; tp = b2 >> 1; step0 = 0; step1 = 2;
    pout = P2 + (size_t)b2 * (128 * 128);
  }
  int td, te; tp2tile(tp, td, te);
  bool diag = (td == te);
  const unsigned short* Ra = R + (size_t)s * slice_stride + (size_t)(td * 128) * KP;
  const unsigned short* Rb = R + (size_t)s * slice_stride + (size_t)(te * 128) * KP;
  int tid = threadIdx.x, wave = tid >> 6, lane = tid & 63;
  int m_off = (wave >> 1) * 64, n_off = (wave & 1) * 64;
  int row_a = m_off + (lane & 15), row_b = n_off + (lane & 15);
  f32x4 acc[4][4];
#pragma unroll
  for (int i = 0; i < 4; ++i)
#pragma unroll
    for (int j = 0; j < 4; ++j) { acc[i][j][0]=0.f; acc[i][j][1]=0.f; acc[i][j][2]=0.f; acc[i][j][3]=0.f; }

  // prologue: stage first tile
  stage_tile(Ra, KP, step0 * 64, Ta[0], wave, lane);
  if (!diag) stage_tile(Rb, KP, step0 * 64, Tb[0], wave, lane);
  __syncthreads();

  int cur = 0;
  for (int kt = step0; kt < step1; ++kt) {
    if (kt + 1 < step1) {                 // prefetch next tile (overlaps MFMA)
      stage_tile(Ra, KP, (kt + 1) * 64, Ta[cur ^ 1], wave, lane);
      if (!diag) stage_tile(Rb, KP, (kt + 1) * 64, Tb[cur ^ 1], wave, lane);
    }
    const unsigned short* Bsrc = diag ? Ta[cur] : Tb[cur];
#pragma unroll
    for (int ks = 0; ks < 2; ++ks) {
      bf16x8 a[4], b[4];
      int slot = ks * 4 + (lane >> 4);
#pragma unroll
      for (int mi = 0; mi < 4; ++mi) a[mi] = read_frag(Ta[cur], row_a + mi * 16, slot);
#pragma unroll
      for (int ni = 0; ni < 4; ++ni) b[ni] = read_frag(Bsrc, row_b + ni * 16, slot);
#pragma unroll
      for (int mi = 0; mi < 4; ++mi)
#pragma unroll
        for (int ni = 0; ni < 4; ++ni)
          acc[mi][ni] = __builtin_amdgcn_mfma_f32_16x16x32_bf16(a[mi], b[ni], acc[mi][ni], 0, 0, 0);
    }
    __syncthreads();   // staged tile landed + all reads of buf[cur] done
    cur ^= 1;
  }
  int hi = lane >> 4, lo = lane & 15;
#pragma unroll
  for (int mi = 0; mi < 4; ++mi)
#pragma unroll
    for (int ni = 0; ni < 4; ++ni)
#pragma unroll
      for (int r = 0; r < 4; ++r) {
        int rr = m_off + mi * 16 + hi * 4 + r;
        int cc = n_off + ni * 16 + lo;
        pout[rr * 128 + cc] = acc[mi][ni][r];
      }
}

// ---------------- K5: 10-way partial sums, grid 672, compile-time KS, NO fence ----------------
template <int KS>
__global__ void __launch_bounds__(256) k5_elem(const float* __restrict__ P1,
                                               const float* __restrict__ P2,
                                               const float* __restrict__ m,
                                               float* __restrict__ bpart, int ksplit_rt) {
  __shared__ float red[4][10];
  int bid = blockIdx.x;                 // 0..671
  int tp = bid >> 5, sub = bid & 31;
  int td, te; tp2tile(tp, td, te);
  bool diagTile = (td == te);
  float mult = diagTile ? 1.0f : 2.0f;
  int t = threadIdx.x;
  int lane = t & 63, w = t >> 6;
  int ksplit = (KS > 0) ? KS : ksplit_rt;
  float v[10];
#pragma unroll
  for (int j = 0; j < 10; ++j) v[j] = 0.f;

#pragma unroll
  for (int k = 0; k < 2; ++k) {
    int idx = sub * 512 + k * 256 + t;   // 0..16383 within tile
    int r = idx >> 7, cc = idx & 127;
    int d = td * 128 + r, e = te * 128 + cc;
    float W[2], B[2];
#pragma unroll
    for (int s = 0; s < 2; ++s) {
      const float* base1 = P1 + (size_t)((tp * 2 + s) * ksplit) * 16384ull + idx;
      float g1 = 0.f;
#pragma unroll
      for (int c6 = 0; c6 < ((KS > 0) ? KS : 16); ++c6) {
        if (KS > 0 || c6 < ksplit) g1 += base1[(size_t)c6 * 16384ull];
      }
      float p2v = P2[(size_t)(tp * 2 + s) * 16384ull + idx];
      W[s] = g1 - 128.0f * p2v - 16384.0f * m[s * 768 + d] * m[s * 768 + e];
      B[s] = p2v;
    }
    v[0] += W[0] * W[0] * mult;  v[1] += W[1] * W[1] * mult;  v[2] += W[0] * W[1] * mult;
    v[3] += B[0] * B[0] * mult;  v[4] += B[1] * B[1] * mult;  v[5] += B[0] * B[1] * mult;
    if (diagTile && r == cc) {
      v[6] += W[0] * W[0];  v[7] += W[1] * W[1];
      v[8] += B[0] * B[0];  v[9] += B[1] * B[1];
    }
  }
#pragma unroll
  for (int off = 32; off; off >>= 1)
#pragma unroll
    for (int j = 0; j < 10; ++j) v[j] += __shfl_down(v[j], off, 64);
  if (lane == 0)
#pragma unroll
    for (int j = 0; j < 10; ++j) red[w][j] = v[j];
  __syncthreads();
  if (t < 10) bpart[bid * 16 + t] = red[0][t] + red[1][t] + red[2][t] + red[3][t];
}

// ---------------- K6: final reduce + normalized combine ----------------
__global__ void __launch_bounds__(256) k6_final(const float* __restrict__ bpart,
                                                float* __restrict__ out) {
  __shared__ float red[4][10];
  float acc[10];
#pragma unroll
  for (int j = 0; j < 10; ++j) acc[j] = 0.f;
  for (int i = threadIdx.x; i < 672; i += 256)
#pragma unroll
    for (int j = 0; j < 10; ++j) acc[j] += bpart[i * 16 + j];
  int lane = threadIdx.x & 63, w = threadIdx.x >> 6;
#pragma unroll
  for (int off = 32; off; off >>= 1)
#pragma unroll
    for (int j = 0; j < 10; ++j) acc[j] += __shfl_down(acc[j], off, 64);
  if (lane == 0)
#pragma unroll
    for (int j = 0; j < 10; ++j) red[w][j] = acc[j];
  __syncthreads();
  if (threadIdx.x == 0) {
    float S[10];
#pragma unroll
    for (int j = 0; j < 10; ++j) S[j] = red[0][j] + red[1][j] + red[2][j] + red[3][j];
    float lw = S[0] / S[6] + S[1] / S[7] - 2.0f * S[2] / sqrtf(S[6] * S[7]);
    float lb = S[3] / S[8] + S[4] / S[9] - 2.0f * S[5] / sqrtf(S[8] * S[9]);
    out[0] = lw + lb;
  }
}

extern "C" void kernel_launch(void* const* d_in, const int* in_sizes, int n_in,
                              void* d_out, int out_size, void* d_ws, size_t ws_size,
                              hipStream_t stream) {
  const float* x = (const float*)d_in[0];
  char* ws = (char*)d_ws;
  unsigned short* RT  = (unsigned short*)(ws + OFF_RT);
  float* xm           = (float*)(ws + OFF_XM);
  float* m            = (float*)(ws + OFF_M);
  unsigned short* rmT = (unsigned short*)(ws + OFF_RM);
  float* P2           = (float*)(ws + OFF_P2);
  float* bpart        = (float*)(ws + OFF_BPART);
  float* P1           = (float*)(ws + OFF_P1);
  float* out          = (float*)d_out;

  // split-K = 12: nbig = 504 = 8*63 -> XCD swizzle bijective & ACTIVE
  size_t availP1 = (ws_size > OFF_P1) ? (ws_size - OFF_P1) : 0;
  int ksplit = (int)(availP1 / (42ull * 128 * 128 * 4));
  if (ksplit > 12) ksplit = 12;
  if (ksplit < 1) ksplit = 1;

  hipLaunchKernelGGL(k1_means_convert, dim3(1536), dim3(256), 0, stream, x, xm, RT);
  hipLaunchKernelGGL(k2_slice_mean, dim3(24), dim3(256), 0, stream, xm, m, rmT);
  hipLaunchKernelGGL(gemm_ata, dim3(42 * ksplit + 42), dim3(256), 0, stream,
                     RT, rmT, P1, P2, ksplit);
  if (ksplit == 12) {
    hipLaunchKernelGGL((k5_elem<12>), dim3(672), dim3(256), 0, stream,
                       P1, P2, m, bpart, ksplit);
  } else if (ksplit == 11) {
    hipLaunchKernelGGL((k5_elem<11>), dim3(672), dim3(256), 0, stream,
                       P1, P2, m, bpart, ksplit);
  } else {
    hipLaunchKernelGGL((k5_elem<0>), dim3(672), dim3(256), 0, stream,
                       P1, P2, m, bpart, ksplit);
  }
  hipLaunchKernelGGL(k6_final, dim3(1), dim3(256), 0, stream, bpart, out);
}